// Round 17
// baseline (238.880 us; speedup 1.0000x reference)
//
#include <hip/hip_runtime.h>

#define BB 32
#define CC 64
#define HH 56
#define WW 56
#define HW 3136
#define TW 64
#define TR 12

// ---------------- prep: pool(8x8 mean) -> wk matmul+bn -> WK = wp * kg^T ----------------
// Single launch (r0 structure): pooling is 4x redundant across g but L3-absorbed,
// and it removes one kernel launch + the pws cross-launch dependency (r6's split
// never measured faster).
__global__ __launch_bounds__(256) void prep_k(const float* __restrict__ x,
                                              const float* __restrict__ wk,
                                              const float* __restrict__ wks,
                                              const float* __restrict__ wkb,
                                              const float* __restrict__ wp_w,
                                              float* __restrict__ WK) {
    __shared__ float p_s[32 * 49];
    __shared__ float kg_s[8 * 49];
    const int b = blockIdx.x >> 2;
    const int g = blockIdx.x & 3;
    const int tid = threadIdx.x;
    for (int idx = tid; idx < 1568; idx += 256) {
        const int i = idx / 49, l = idx % 49;
        const int py = l / 7, px = l % 7;
        const float4* xp4 = reinterpret_cast<const float4*>(
            x + ((long)(b * CC + 32 + i)) * HW + py * 8 * WW + px * 8);
        float4 sA = make_float4(0.f, 0.f, 0.f, 0.f);
        float4 sB = make_float4(0.f, 0.f, 0.f, 0.f);
        #pragma unroll
        for (int y = 0; y < 8; ++y) {
            const float4 a = xp4[y * 14];
            const float4 c = xp4[y * 14 + 1];
            sA.x += a.x; sA.y += a.y; sA.z += a.z; sA.w += a.w;
            sB.x += c.x; sB.y += c.y; sB.z += c.z; sB.w += c.w;
        }
        p_s[idx] = (sA.x + sA.y + sA.z + sA.w + sB.x + sB.y + sB.z + sB.w) * (1.f / 64.f);
    }
    __syncthreads();
    for (int idx = tid; idx < 392; idx += 256) {
        const int o8 = idx / 49, l = idx % 49;
        const int o = g * 8 + o8;
        float acc = 0.f;
        #pragma unroll
        for (int i = 0; i < 32; ++i) acc = fmaf(wk[o * 32 + i], p_s[i * 49 + l], acc);
        kg_s[idx] = acc * wks[o] + wkb[o];
    }
    __syncthreads();
    for (int idx = tid; idx < 640; idx += 256) {
        const int c = idx / 80, slot = idx % 80;
        float acc = 0.f;
        int m = -1;
        if (slot < 28) { if (slot < 25) m = slot; }
        else           { if (slot < 77) m = 25 + (slot - 28); }
        if (m >= 0) {
            const float* kp = kg_s + c * 49;
            #pragma unroll
            for (int l = 0; l < 49; ++l) acc = fmaf(wp_w[m * 49 + l], kp[l], acc);
        }
        const long base = (long)blockIdx.x * 640;
        if (slot < 28) WK[base + c * 28 + slot] = acc;
        else           WK[base + 224 + c * 52 + (slot - 28)] = acc;
    }
}

// ---------------- fused q-proj + attention + dyn_mix + lepe ----------------
// r13 kernel verbatim (best verified: ~102 us, VGPR 60, occ 31%): 2-way ILP split of
// gather accumulators (even/odd rows) + 2-way softmax max/sum trees.
__global__ __launch_bounds__(256) void attnmix_k(const float* __restrict__ x,
                                                 const float* __restrict__ WK,
                                                 const float* __restrict__ wq_w,
                                                 const float* __restrict__ wq_s,
                                                 const float* __restrict__ wq_bb,
                                                 const float* __restrict__ wp_b,
                                                 const float* __restrict__ rpb1,
                                                 const float* __restrict__ rpb2,
                                                 const float* __restrict__ lw,
                                                 const float* __restrict__ lb,
                                                 const float* __restrict__ ls,
                                                 const float* __restrict__ lbb,
                                                 float* __restrict__ mix,
                                                 float* __restrict__ out) {
    __shared__ float tile[8 * TR * TW];   // 24 KB
    __shared__ float WK1_s[8 * 28];
    __shared__ float WK2_s[8 * 52];
    __shared__ float wqT_s[32 * 8];
    __shared__ float wpb1_s[25];
    __shared__ float wpb2_s[49];
    __shared__ float rpb1_s[81];
    __shared__ float rpb2_s[169];
    __shared__ float wqbn_s[16];
    __shared__ float lw_s[8 * 49];        // per-phase lepe weights (reloaded at phase 2)
    __shared__ float lbn_s[48];           // [0..15]=b, [16..31]=s, [32..47]=bb
    const int tid = threadIdx.x;
    const int bg = blockIdx.y;
    const int g = bg & 3, b = bg >> 2;

    {
        const float* wkp = WK + (long)bg * 640;
        for (int i = tid; i < 224; i += 256) WK1_s[i] = wkp[i];
        for (int i = tid; i < 416; i += 256) WK2_s[i] = wkp[224 + i];
    }
    {
        const int i = tid >> 3, c = tid & 7;
        wqT_s[tid] = wq_w[(g * 8 + c) * 32 + i];
    }
    if (tid < 25) wpb1_s[tid] = wp_b[tid];
    if (tid >= 32 && tid < 81) wpb2_s[tid - 32] = wp_b[25 + tid - 32];
    if (tid < 81) rpb1_s[tid] = rpb1[g * 81 + tid];
    if (tid < 169) rpb2_s[tid] = rpb2[g * 169 + tid];
    if (tid >= 192 && tid < 200) wqbn_s[tid - 192] = wq_s[g * 8 + tid - 192];
    if (tid >= 200 && tid < 208) wqbn_s[8 + tid - 200] = wq_bb[g * 8 + tid - 200];
    for (int i = tid; i < 392; i += 256) lw_s[i] = lw[(g * 8) * 49 + i];   // phase-1 chans
    if (tid < 16) {
        const int c = (tid < 8) ? (g * 8 + tid) : (32 + g * 8 + tid - 8);
        lbn_s[tid] = lb[c]; lbn_s[16 + tid] = ls[c]; lbn_s[32 + tid] = lbb[c];
    }

    const int N0 = blockIdx.x << 8;
    const int ph0 = N0 / WW;             // block-uniform
    const int r0 = ph0 - 3;

    // ---- stage v0 tile (channels g*8 .. g*8+8) ----
    {
        const float* xc = x + ((long)b * CC + g * 8) * HW;
        #pragma unroll
        for (int ch = 0; ch < 8; ++ch)
            for (int k = tid; k < TR * TW; k += 256) {
                const int row = k >> 6, lxx = k & 63;
                const int gy = r0 + row, gx = lxx - 3;
                float v = 0.f;
                if ((unsigned)gy < HH && (unsigned)gx < WW) v = xc[ch * HW + gy * WW + gx];
                tile[ch * (TR * TW) + k] = v;
            }
    }
    __syncthreads();

    const int n = N0 + tid;
    const bool valid = n < HW;
    const int nc = valid ? n : HW - 1;
    const int ph = nc / WW, pw = nc % WW;
    const int yr = HH - 1 - ph, xr = WW - 1 - pw;
    const int lrow = ph - r0;            // in [3, 8]
    const int tb0 = (lrow - 3) * TW + pw;   // tile offset of tap (i=0,j=0)

    const float* xb = x + (long)b * CC * HW + nc;

    // ---- q8: q = wq . x[0..32), bn, *SCALE ----
    float q8[8];
    #pragma unroll
    for (int c = 0; c < 8; ++c) q8[c] = 0.f;
    for (int i = 0; i < 32; ++i) {
        const float xv = xb[i * HW];
        #pragma unroll
        for (int c = 0; c < 8; ++c) q8[c] = fmaf(wqT_s[i * 8 + c], xv, q8[c]);
    }
    #pragma unroll
    for (int c = 0; c < 8; ++c)
        q8[c] = (q8[c] * wqbn_s[c] + wqbn_s[8 + c]) * 0.25f;

    __builtin_amdgcn_sched_barrier(0);

    // ======== phase 1: 25-weight softmax, 5x5 gather + lepe 7x7 over v0 ========
    {
        float w1[25];
        #pragma unroll
        for (int m = 0; m < 25; ++m) w1[m] = wpb1_s[m];
        #pragma unroll
        for (int c = 0; c < 8; ++c) {
            const float qv = q8[c];
            #pragma unroll
            for (int m = 0; m < 25; ++m) w1[m] = fmaf(qv, WK1_s[c * 28 + m], w1[m]);
        }
        const int rh5 = yr < 2 ? yr : (yr > 53 ? yr - 51 : 2);
        const int rw5 = xr < 2 ? xr : (xr > 53 ? xr - 51 : 2);
        #pragma unroll
        for (int i = 0; i < 5; ++i)
            #pragma unroll
            for (int j = 0; j < 5; ++j)
                w1[i * 5 + j] += rpb1_s[(rh5 + i) * 9 + (rw5 + j)];
        float mxa = -1e30f, mxb = -1e30f;
        #pragma unroll
        for (int m = 0; m < 24; m += 2) { mxa = fmaxf(mxa, w1[m]); mxb = fmaxf(mxb, w1[m + 1]); }
        const float mx = fmaxf(fmaxf(mxa, mxb), w1[24]);
        float sma = 0.f, smb = 0.f;
        #pragma unroll
        for (int m = 0; m < 24; m += 2) {
            w1[m] = __expf(w1[m] - mx);     sma += w1[m];
            w1[m + 1] = __expf(w1[m + 1] - mx); smb += w1[m + 1];
        }
        w1[24] = __expf(w1[24] - mx);
        const float r = 1.f / (sma + smb + w1[24]);
        #pragma unroll
        for (int m = 0; m < 25; ++m) w1[m] *= r;

        float* m0 = mix + ((long)b * CC + g * 8) * HW + nc;
        float* o0 = out + ((long)b * CC + g * 8) * HW + nc;
        #pragma unroll
        for (int ch = 0; ch < 8; ++ch) {
            const float* t = tile + ch * (TR * TW) + tb0;
            const float* lwc = lw_s + ch * 49;
            float a_e = 0.f, a_o = 0.f, la_e = 0.f, la_o = 0.f;
            #pragma unroll
            for (int i = 0; i < 7; ++i)
                #pragma unroll
                for (int j = 0; j < 7; ++j) {
                    const float v = t[i * TW + j];
                    if (i & 1) {
                        la_o = fmaf(lwc[i * 7 + j], v, la_o);
                        if (i <= 5 && j >= 1 && j <= 5)
                            a_o = fmaf(w1[(i - 1) * 5 + (j - 1)], v, a_o);
                    } else {
                        la_e = fmaf(lwc[i * 7 + j], v, la_e);
                        if (i >= 1 && i <= 5 && j >= 1 && j <= 5)
                            a_e = fmaf(w1[(i - 1) * 5 + (j - 1)], v, a_e);
                    }
                }
            if (valid) {
                m0[ch * HW] = a_e + a_o;
                o0[ch * HW] = ((la_e + la_o) + lbn_s[ch]) * lbn_s[16 + ch] + lbn_s[32 + ch];
            }
        }
    }

    __syncthreads();                      // tile + lw reads done
    // ---- re-stage tile with v1 channels (32 + g*8 ..) + phase-2 lepe weights ----
    {
        const float* xc = x + ((long)b * CC + 32 + g * 8) * HW;
        #pragma unroll
        for (int ch = 0; ch < 8; ++ch)
            for (int k = tid; k < TR * TW; k += 256) {
                const int row = k >> 6, lxx = k & 63;
                const int gy = r0 + row, gx = lxx - 3;
                float v = 0.f;
                if ((unsigned)gy < HH && (unsigned)gx < WW) v = xc[ch * HW + gy * WW + gx];
                tile[ch * (TR * TW) + k] = v;
            }
        for (int i = tid; i < 392; i += 256) lw_s[i] = lw[(32 + g * 8) * 49 + i];
    }
    __syncthreads();

    // ======== phase 2: 49-weight softmax, 7x7 gather + lepe 7x7 over v1 ========
    {
        float w2[49];
        #pragma unroll
        for (int m = 0; m < 49; ++m) w2[m] = wpb2_s[m];
        #pragma unroll
        for (int c = 0; c < 8; ++c) {
            const float qv = q8[c];
            #pragma unroll
            for (int m = 0; m < 49; ++m) w2[m] = fmaf(qv, WK2_s[c * 52 + m], w2[m]);
        }
        const int rh7 = yr < 3 ? yr : (yr > 52 ? yr - 49 : 3);
        const int rw7 = xr < 3 ? xr : (xr > 52 ? xr - 49 : 3);
        #pragma unroll
        for (int i = 0; i < 7; ++i)
            #pragma unroll
            for (int j = 0; j < 7; ++j)
                w2[i * 7 + j] += rpb2_s[(rh7 + i) * 13 + (rw7 + j)];
        float mxa = -1e30f, mxb = -1e30f;
        #pragma unroll
        for (int m = 0; m < 48; m += 2) { mxa = fmaxf(mxa, w2[m]); mxb = fmaxf(mxb, w2[m + 1]); }
        const float mx = fmaxf(fmaxf(mxa, mxb), w2[48]);
        float sma = 0.f, smb = 0.f;
        #pragma unroll
        for (int m = 0; m < 48; m += 2) {
            w2[m] = __expf(w2[m] - mx);     sma += w2[m];
            w2[m + 1] = __expf(w2[m + 1] - mx); smb += w2[m + 1];
        }
        w2[48] = __expf(w2[48] - mx);
        const float r = 1.f / (sma + smb + w2[48]);
        #pragma unroll
        for (int m = 0; m < 49; ++m) w2[m] *= r;

        float* m1 = mix + ((long)b * CC + 32 + g * 8) * HW + nc;
        float* o1 = out + ((long)b * CC + 32 + g * 8) * HW + nc;
        #pragma unroll
        for (int ch = 0; ch < 8; ++ch) {
            const float* t = tile + ch * (TR * TW) + tb0;
            const float* lwc = lw_s + ch * 49;
            float a_e = 0.f, a_o = 0.f, la_e = 0.f, la_o = 0.f;
            #pragma unroll
            for (int i = 0; i < 7; ++i)
                #pragma unroll
                for (int j = 0; j < 7; ++j) {
                    const float v = t[i * TW + j];
                    if (i & 1) {
                        la_o = fmaf(lwc[i * 7 + j], v, la_o);
                        a_o  = fmaf(w2[i * 7 + j], v, a_o);
                    } else {
                        la_e = fmaf(lwc[i * 7 + j], v, la_e);
                        a_e  = fmaf(w2[i * 7 + j], v, a_e);
                    }
                }
            if (valid) {
                m1[ch * HW] = a_e + a_o;
                o1[ch * HW] = ((la_e + la_o) + lbn_s[8 + ch]) * lbn_s[16 + 8 + ch] + lbn_s[32 + 8 + ch];
            }
        }
    }
}

// ---------------- final: 64x64 channel matmul + bn + lepe add ----------------
__global__ __launch_bounds__(256) void final_k(const float* __restrict__ mix,
                                               const float* __restrict__ dy_w,
                                               const float* __restrict__ s,
                                               const float* __restrict__ bb,
                                               float* __restrict__ out) {
    __shared__ float w_s[64 * 64];      // transposed: w_s[i*64+o] = dy_w[o*64+i]
    const int tid = threadIdx.x;
    const int b = blockIdx.y;
    for (int i = tid; i < 4096; i += 256) w_s[(i & 63) * 64 + (i >> 6)] = dy_w[i];
    __syncthreads();
    const int oo = (tid >> 5) * 8;
    const int p4 = blockIdx.x * 32 + (tid & 31);
    if (p4 >= 784) return;
    const float* mp = mix + (long)b * CC * HW + p4 * 4;
    float4 acc[8];
    #pragma unroll
    for (int o = 0; o < 8; ++o) acc[o] = make_float4(0.f, 0.f, 0.f, 0.f);
    for (int ii = 0; ii < 64; ii += 8) {
        float4 mv[8];
        #pragma unroll
        for (int u = 0; u < 8; ++u)
            mv[u] = *reinterpret_cast<const float4*>(mp + (long)(ii + u) * HW);
        #pragma unroll
        for (int u = 0; u < 8; ++u) {
            const float* wr = w_s + (ii + u) * 64 + oo;
            #pragma unroll
            for (int o = 0; o < 8; ++o) {
                const float wv = wr[o];
                acc[o].x = fmaf(wv, mv[u].x, acc[o].x);
                acc[o].y = fmaf(wv, mv[u].y, acc[o].y);
                acc[o].z = fmaf(wv, mv[u].z, acc[o].z);
                acc[o].w = fmaf(wv, mv[u].w, acc[o].w);
            }
        }
    }
    float* op = out + (long)b * CC * HW + p4 * 4;
    #pragma unroll
    for (int o = 0; o < 8; ++o) {
        const float sc = s[oo + o], bc = bb[oo + o];
        float4* dst = reinterpret_cast<float4*>(op + (long)(oo + o) * HW);
        float4 prev = *dst;
        prev.x = fmaf(acc[o].x, sc, bc) + prev.x;
        prev.y = fmaf(acc[o].y, sc, bc) + prev.y;
        prev.z = fmaf(acc[o].z, sc, bc) + prev.z;
        prev.w = fmaf(acc[o].w, sc, bc) + prev.w;
        *dst = prev;
    }
}

extern "C" void kernel_launch(void* const* d_in, const int* in_sizes, int n_in,
                              void* d_out, int out_size, void* d_ws, size_t ws_size,
                              hipStream_t stream) {
    const float* x       = (const float*)d_in[0];
    const float* lepe_w  = (const float*)d_in[1];
    const float* lepe_b  = (const float*)d_in[2];
    const float* lepe_s  = (const float*)d_in[3];
    const float* lepe_bb = (const float*)d_in[4];
    const float* wq_w    = (const float*)d_in[5];
    const float* wq_s    = (const float*)d_in[6];
    const float* wq_bb   = (const float*)d_in[7];
    const float* wk_w    = (const float*)d_in[8];
    const float* wk_s    = (const float*)d_in[9];
    const float* wk_bb   = (const float*)d_in[10];
    const float* wp_w    = (const float*)d_in[11];
    const float* wp_b    = (const float*)d_in[12];
    const float* rpb1    = (const float*)d_in[13];
    const float* rpb2    = (const float*)d_in[14];
    const float* dy_w    = (const float*)d_in[15];
    const float* dy_s    = (const float*)d_in[16];
    const float* dy_bb   = (const float*)d_in[17];
    float* out = (float*)d_out;

    float* ws     = (float*)d_ws;
    float* WK_ws  = ws;                               // 128*640   =    81,920 f
    float* mix_ws = WK_ws + 128 * 640;                // 32*64*3136 = 6,422,528 f

    const int nTiles = (HW + 255) / 256;              // 13

    prep_k<<<dim3(BB * 4), 256, 0, stream>>>(x, wk_w, wk_s, wk_bb, wp_w, WK_ws);
    attnmix_k<<<dim3(nTiles, BB * 4), 256, 0, stream>>>(x, WK_ws, wq_w, wq_s, wq_bb,
                                                        wp_b, rpb1, rpb2,
                                                        lepe_w, lepe_b, lepe_s, lepe_bb,
                                                        mix_ws, out);
    final_k<<<dim3(25, BB), 256, 0, stream>>>(mix_ws, dy_w, dy_s, dy_bb, out);
}

// Round 18
// 230.052 us; speedup vs baseline: 1.0384x; 1.0384x over previous
//
#include <hip/hip_runtime.h>

#define BB 32
#define CC 64
#define HH 56
#define WW 56
#define HW 3136
#define TW 64
#define TR 12

// bf16 round-to-nearest-even pack/unpack (mix intermediate only)
__device__ __forceinline__ unsigned short f2bf(float f) {
    unsigned int u = __float_as_uint(f);
    u = (u + 0x7FFFu + ((u >> 16) & 1u)) >> 16;
    return (unsigned short)u;
}
__device__ __forceinline__ float bf2f(unsigned short h) {
    return __uint_as_float(((unsigned int)h) << 16);
}

// ---------------- prep: pool(8x8 mean) -> wk matmul+bn -> WK = wp * kg^T ----------------
__global__ __launch_bounds__(256) void prep_k(const float* __restrict__ x,
                                              const float* __restrict__ wk,
                                              const float* __restrict__ wks,
                                              const float* __restrict__ wkb,
                                              const float* __restrict__ wp_w,
                                              float* __restrict__ WK) {
    __shared__ float p_s[32 * 49];
    __shared__ float kg_s[8 * 49];
    const int b = blockIdx.x >> 2;
    const int g = blockIdx.x & 3;
    const int tid = threadIdx.x;
    for (int idx = tid; idx < 1568; idx += 256) {
        const int i = idx / 49, l = idx % 49;
        const int py = l / 7, px = l % 7;
        const float4* xp4 = reinterpret_cast<const float4*>(
            x + ((long)(b * CC + 32 + i)) * HW + py * 8 * WW + px * 8);
        float4 sA = make_float4(0.f, 0.f, 0.f, 0.f);
        float4 sB = make_float4(0.f, 0.f, 0.f, 0.f);
        #pragma unroll
        for (int y = 0; y < 8; ++y) {
            const float4 a = xp4[y * 14];
            const float4 c = xp4[y * 14 + 1];
            sA.x += a.x; sA.y += a.y; sA.z += a.z; sA.w += a.w;
            sB.x += c.x; sB.y += c.y; sB.z += c.z; sB.w += c.w;
        }
        p_s[idx] = (sA.x + sA.y + sA.z + sA.w + sB.x + sB.y + sB.z + sB.w) * (1.f / 64.f);
    }
    __syncthreads();
    for (int idx = tid; idx < 392; idx += 256) {
        const int o8 = idx / 49, l = idx % 49;
        const int o = g * 8 + o8;
        float acc = 0.f;
        #pragma unroll
        for (int i = 0; i < 32; ++i) acc = fmaf(wk[o * 32 + i], p_s[i * 49 + l], acc);
        kg_s[idx] = acc * wks[o] + wkb[o];
    }
    __syncthreads();
    for (int idx = tid; idx < 640; idx += 256) {
        const int c = idx / 80, slot = idx % 80;
        float acc = 0.f;
        int m = -1;
        if (slot < 28) { if (slot < 25) m = slot; }
        else           { if (slot < 77) m = 25 + (slot - 28); }
        if (m >= 0) {
            const float* kp = kg_s + c * 49;
            #pragma unroll
            for (int l = 0; l < 49; ++l) acc = fmaf(wp_w[m * 49 + l], kp[l], acc);
        }
        const long base = (long)blockIdx.x * 640;
        if (slot < 28) WK[base + c * 28 + slot] = acc;
        else           WK[base + 224 + c * 52 + (slot - 28)] = acc;
    }
}

// ---------------- fused q-proj + attention + dyn_mix + lepe ----------------
// r13/r17 kernel verbatim except mix is stored as bf16 (RNE), halving the
// intermediate's HBM write (and final's read).
__global__ __launch_bounds__(256) void attnmix_k(const float* __restrict__ x,
                                                 const float* __restrict__ WK,
                                                 const float* __restrict__ wq_w,
                                                 const float* __restrict__ wq_s,
                                                 const float* __restrict__ wq_bb,
                                                 const float* __restrict__ wp_b,
                                                 const float* __restrict__ rpb1,
                                                 const float* __restrict__ rpb2,
                                                 const float* __restrict__ lw,
                                                 const float* __restrict__ lb,
                                                 const float* __restrict__ ls,
                                                 const float* __restrict__ lbb,
                                                 unsigned short* __restrict__ mix,
                                                 float* __restrict__ out) {
    __shared__ float tile[8 * TR * TW];   // 24 KB
    __shared__ float WK1_s[8 * 28];
    __shared__ float WK2_s[8 * 52];
    __shared__ float wqT_s[32 * 8];
    __shared__ float wpb1_s[25];
    __shared__ float wpb2_s[49];
    __shared__ float rpb1_s[81];
    __shared__ float rpb2_s[169];
    __shared__ float wqbn_s[16];
    __shared__ float lw_s[8 * 49];        // per-phase lepe weights (reloaded at phase 2)
    __shared__ float lbn_s[48];           // [0..15]=b, [16..31]=s, [32..47]=bb
    const int tid = threadIdx.x;
    const int bg = blockIdx.y;
    const int g = bg & 3, b = bg >> 2;

    {
        const float* wkp = WK + (long)bg * 640;
        for (int i = tid; i < 224; i += 256) WK1_s[i] = wkp[i];
        for (int i = tid; i < 416; i += 256) WK2_s[i] = wkp[224 + i];
    }
    {
        const int i = tid >> 3, c = tid & 7;
        wqT_s[tid] = wq_w[(g * 8 + c) * 32 + i];
    }
    if (tid < 25) wpb1_s[tid] = wp_b[tid];
    if (tid >= 32 && tid < 81) wpb2_s[tid - 32] = wp_b[25 + tid - 32];
    if (tid < 81) rpb1_s[tid] = rpb1[g * 81 + tid];
    if (tid < 169) rpb2_s[tid] = rpb2[g * 169 + tid];
    if (tid >= 192 && tid < 200) wqbn_s[tid - 192] = wq_s[g * 8 + tid - 192];
    if (tid >= 200 && tid < 208) wqbn_s[8 + tid - 200] = wq_bb[g * 8 + tid - 200];
    for (int i = tid; i < 392; i += 256) lw_s[i] = lw[(g * 8) * 49 + i];   // phase-1 chans
    if (tid < 16) {
        const int c = (tid < 8) ? (g * 8 + tid) : (32 + g * 8 + tid - 8);
        lbn_s[tid] = lb[c]; lbn_s[16 + tid] = ls[c]; lbn_s[32 + tid] = lbb[c];
    }

    const int N0 = blockIdx.x << 8;
    const int ph0 = N0 / WW;             // block-uniform
    const int r0 = ph0 - 3;

    // ---- stage v0 tile (channels g*8 .. g*8+8) ----
    {
        const float* xc = x + ((long)b * CC + g * 8) * HW;
        #pragma unroll
        for (int ch = 0; ch < 8; ++ch)
            for (int k = tid; k < TR * TW; k += 256) {
                const int row = k >> 6, lxx = k & 63;
                const int gy = r0 + row, gx = lxx - 3;
                float v = 0.f;
                if ((unsigned)gy < HH && (unsigned)gx < WW) v = xc[ch * HW + gy * WW + gx];
                tile[ch * (TR * TW) + k] = v;
            }
    }
    __syncthreads();

    const int n = N0 + tid;
    const bool valid = n < HW;
    const int nc = valid ? n : HW - 1;
    const int ph = nc / WW, pw = nc % WW;
    const int yr = HH - 1 - ph, xr = WW - 1 - pw;
    const int lrow = ph - r0;            // in [3, 8]
    const int tb0 = (lrow - 3) * TW + pw;   // tile offset of tap (i=0,j=0)

    const float* xb = x + (long)b * CC * HW + nc;

    // ---- q8: q = wq . x[0..32), bn, *SCALE ----
    float q8[8];
    #pragma unroll
    for (int c = 0; c < 8; ++c) q8[c] = 0.f;
    for (int i = 0; i < 32; ++i) {
        const float xv = xb[i * HW];
        #pragma unroll
        for (int c = 0; c < 8; ++c) q8[c] = fmaf(wqT_s[i * 8 + c], xv, q8[c]);
    }
    #pragma unroll
    for (int c = 0; c < 8; ++c)
        q8[c] = (q8[c] * wqbn_s[c] + wqbn_s[8 + c]) * 0.25f;

    __builtin_amdgcn_sched_barrier(0);

    // ======== phase 1: 25-weight softmax, 5x5 gather + lepe 7x7 over v0 ========
    {
        float w1[25];
        #pragma unroll
        for (int m = 0; m < 25; ++m) w1[m] = wpb1_s[m];
        #pragma unroll
        for (int c = 0; c < 8; ++c) {
            const float qv = q8[c];
            #pragma unroll
            for (int m = 0; m < 25; ++m) w1[m] = fmaf(qv, WK1_s[c * 28 + m], w1[m]);
        }
        const int rh5 = yr < 2 ? yr : (yr > 53 ? yr - 51 : 2);
        const int rw5 = xr < 2 ? xr : (xr > 53 ? xr - 51 : 2);
        #pragma unroll
        for (int i = 0; i < 5; ++i)
            #pragma unroll
            for (int j = 0; j < 5; ++j)
                w1[i * 5 + j] += rpb1_s[(rh5 + i) * 9 + (rw5 + j)];
        float mxa = -1e30f, mxb = -1e30f;
        #pragma unroll
        for (int m = 0; m < 24; m += 2) { mxa = fmaxf(mxa, w1[m]); mxb = fmaxf(mxb, w1[m + 1]); }
        const float mx = fmaxf(fmaxf(mxa, mxb), w1[24]);
        float sma = 0.f, smb = 0.f;
        #pragma unroll
        for (int m = 0; m < 24; m += 2) {
            w1[m] = __expf(w1[m] - mx);     sma += w1[m];
            w1[m + 1] = __expf(w1[m + 1] - mx); smb += w1[m + 1];
        }
        w1[24] = __expf(w1[24] - mx);
        const float r = 1.f / (sma + smb + w1[24]);
        #pragma unroll
        for (int m = 0; m < 25; ++m) w1[m] *= r;

        unsigned short* m0 = mix + ((long)b * CC + g * 8) * HW + nc;
        float* o0 = out + ((long)b * CC + g * 8) * HW + nc;
        #pragma unroll
        for (int ch = 0; ch < 8; ++ch) {
            const float* t = tile + ch * (TR * TW) + tb0;
            const float* lwc = lw_s + ch * 49;
            float a_e = 0.f, a_o = 0.f, la_e = 0.f, la_o = 0.f;
            #pragma unroll
            for (int i = 0; i < 7; ++i)
                #pragma unroll
                for (int j = 0; j < 7; ++j) {
                    const float v = t[i * TW + j];
                    if (i & 1) {
                        la_o = fmaf(lwc[i * 7 + j], v, la_o);
                        if (i <= 5 && j >= 1 && j <= 5)
                            a_o = fmaf(w1[(i - 1) * 5 + (j - 1)], v, a_o);
                    } else {
                        la_e = fmaf(lwc[i * 7 + j], v, la_e);
                        if (i >= 1 && i <= 5 && j >= 1 && j <= 5)
                            a_e = fmaf(w1[(i - 1) * 5 + (j - 1)], v, a_e);
                    }
                }
            if (valid) {
                m0[ch * HW] = f2bf(a_e + a_o);
                o0[ch * HW] = ((la_e + la_o) + lbn_s[ch]) * lbn_s[16 + ch] + lbn_s[32 + ch];
            }
        }
    }

    __syncthreads();                      // tile + lw reads done
    // ---- re-stage tile with v1 channels (32 + g*8 ..) + phase-2 lepe weights ----
    {
        const float* xc = x + ((long)b * CC + 32 + g * 8) * HW;
        #pragma unroll
        for (int ch = 0; ch < 8; ++ch)
            for (int k = tid; k < TR * TW; k += 256) {
                const int row = k >> 6, lxx = k & 63;
                const int gy = r0 + row, gx = lxx - 3;
                float v = 0.f;
                if ((unsigned)gy < HH && (unsigned)gx < WW) v = xc[ch * HW + gy * WW + gx];
                tile[ch * (TR * TW) + k] = v;
            }
        for (int i = tid; i < 392; i += 256) lw_s[i] = lw[(32 + g * 8) * 49 + i];
    }
    __syncthreads();

    // ======== phase 2: 49-weight softmax, 7x7 gather + lepe 7x7 over v1 ========
    {
        float w2[49];
        #pragma unroll
        for (int m = 0; m < 49; ++m) w2[m] = wpb2_s[m];
        #pragma unroll
        for (int c = 0; c < 8; ++c) {
            const float qv = q8[c];
            #pragma unroll
            for (int m = 0; m < 49; ++m) w2[m] = fmaf(qv, WK2_s[c * 52 + m], w2[m]);
        }
        const int rh7 = yr < 3 ? yr : (yr > 52 ? yr - 49 : 3);
        const int rw7 = xr < 3 ? xr : (xr > 52 ? xr - 49 : 3);
        #pragma unroll
        for (int i = 0; i < 7; ++i)
            #pragma unroll
            for (int j = 0; j < 7; ++j)
                w2[i * 7 + j] += rpb2_s[(rh7 + i) * 13 + (rw7 + j)];
        float mxa = -1e30f, mxb = -1e30f;
        #pragma unroll
        for (int m = 0; m < 48; m += 2) { mxa = fmaxf(mxa, w2[m]); mxb = fmaxf(mxb, w2[m + 1]); }
        const float mx = fmaxf(fmaxf(mxa, mxb), w2[48]);
        float sma = 0.f, smb = 0.f;
        #pragma unroll
        for (int m = 0; m < 48; m += 2) {
            w2[m] = __expf(w2[m] - mx);     sma += w2[m];
            w2[m + 1] = __expf(w2[m + 1] - mx); smb += w2[m + 1];
        }
        w2[48] = __expf(w2[48] - mx);
        const float r = 1.f / (sma + smb + w2[48]);
        #pragma unroll
        for (int m = 0; m < 49; ++m) w2[m] *= r;

        unsigned short* m1 = mix + ((long)b * CC + 32 + g * 8) * HW + nc;
        float* o1 = out + ((long)b * CC + 32 + g * 8) * HW + nc;
        #pragma unroll
        for (int ch = 0; ch < 8; ++ch) {
            const float* t = tile + ch * (TR * TW) + tb0;
            const float* lwc = lw_s + ch * 49;
            float a_e = 0.f, a_o = 0.f, la_e = 0.f, la_o = 0.f;
            #pragma unroll
            for (int i = 0; i < 7; ++i)
                #pragma unroll
                for (int j = 0; j < 7; ++j) {
                    const float v = t[i * TW + j];
                    if (i & 1) {
                        la_o = fmaf(lwc[i * 7 + j], v, la_o);
                        a_o  = fmaf(w2[i * 7 + j], v, a_o);
                    } else {
                        la_e = fmaf(lwc[i * 7 + j], v, la_e);
                        a_e  = fmaf(w2[i * 7 + j], v, a_e);
                    }
                }
            if (valid) {
                m1[ch * HW] = f2bf(a_e + a_o);
                o1[ch * HW] = ((la_e + la_o) + lbn_s[8 + ch]) * lbn_s[16 + 8 + ch] + lbn_s[32 + 8 + ch];
            }
        }
    }
}

// ---------------- final: 64x64 channel matmul + bn + lepe add (bf16 mix in) ----------------
__global__ __launch_bounds__(256) void final_k(const unsigned short* __restrict__ mix,
                                               const float* __restrict__ dy_w,
                                               const float* __restrict__ s,
                                               const float* __restrict__ bb,
                                               float* __restrict__ out) {
    __shared__ float w_s[64 * 64];      // transposed: w_s[i*64+o] = dy_w[o*64+i]
    const int tid = threadIdx.x;
    const int b = blockIdx.y;
    for (int i = tid; i < 4096; i += 256) w_s[(i & 63) * 64 + (i >> 6)] = dy_w[i];
    __syncthreads();
    const int oo = (tid >> 5) * 8;
    const int p4 = blockIdx.x * 32 + (tid & 31);
    if (p4 >= 784) return;
    const unsigned short* mp = mix + (long)b * CC * HW + p4 * 4;
    float4 acc[8];
    #pragma unroll
    for (int o = 0; o < 8; ++o) acc[o] = make_float4(0.f, 0.f, 0.f, 0.f);
    for (int ii = 0; ii < 64; ii += 8) {
        float4 mv[8];
        #pragma unroll
        for (int u = 0; u < 8; ++u) {
            const ushort4 h = *reinterpret_cast<const ushort4*>(mp + (long)(ii + u) * HW);
            mv[u].x = bf2f(h.x); mv[u].y = bf2f(h.y);
            mv[u].z = bf2f(h.z); mv[u].w = bf2f(h.w);
        }
        #pragma unroll
        for (int u = 0; u < 8; ++u) {
            const float* wr = w_s + (ii + u) * 64 + oo;
            #pragma unroll
            for (int o = 0; o < 8; ++o) {
                const float wv = wr[o];
                acc[o].x = fmaf(wv, mv[u].x, acc[o].x);
                acc[o].y = fmaf(wv, mv[u].y, acc[o].y);
                acc[o].z = fmaf(wv, mv[u].z, acc[o].z);
                acc[o].w = fmaf(wv, mv[u].w, acc[o].w);
            }
        }
    }
    float* op = out + (long)b * CC * HW + p4 * 4;
    #pragma unroll
    for (int o = 0; o < 8; ++o) {
        const float sc = s[oo + o], bc = bb[oo + o];
        float4* dst = reinterpret_cast<float4*>(op + (long)(oo + o) * HW);
        float4 prev = *dst;
        prev.x = fmaf(acc[o].x, sc, bc) + prev.x;
        prev.y = fmaf(acc[o].y, sc, bc) + prev.y;
        prev.z = fmaf(acc[o].z, sc, bc) + prev.z;
        prev.w = fmaf(acc[o].w, sc, bc) + prev.w;
        *dst = prev;
    }
}

extern "C" void kernel_launch(void* const* d_in, const int* in_sizes, int n_in,
                              void* d_out, int out_size, void* d_ws, size_t ws_size,
                              hipStream_t stream) {
    const float* x       = (const float*)d_in[0];
    const float* lepe_w  = (const float*)d_in[1];
    const float* lepe_b  = (const float*)d_in[2];
    const float* lepe_s  = (const float*)d_in[3];
    const float* lepe_bb = (const float*)d_in[4];
    const float* wq_w    = (const float*)d_in[5];
    const float* wq_s    = (const float*)d_in[6];
    const float* wq_bb   = (const float*)d_in[7];
    const float* wk_w    = (const float*)d_in[8];
    const float* wk_s    = (const float*)d_in[9];
    const float* wk_bb   = (const float*)d_in[10];
    const float* wp_w    = (const float*)d_in[11];
    const float* wp_b    = (const float*)d_in[12];
    const float* rpb1    = (const float*)d_in[13];
    const float* rpb2    = (const float*)d_in[14];
    const float* dy_w    = (const float*)d_in[15];
    const float* dy_s    = (const float*)d_in[16];
    const float* dy_bb   = (const float*)d_in[17];
    float* out = (float*)d_out;

    float* ws     = (float*)d_ws;
    float* WK_ws  = ws;                               // 128*640 floats
    unsigned short* mix_ws = (unsigned short*)(WK_ws + 128 * 640);  // 32*64*3136 bf16

    const int nTiles = (HW + 255) / 256;              // 13

    prep_k<<<dim3(BB * 4), 256, 0, stream>>>(x, wk_w, wk_s, wk_bb, wp_w, WK_ws);
    attnmix_k<<<dim3(nTiles, BB * 4), 256, 0, stream>>>(x, WK_ws, wq_w, wq_s, wq_bb,
                                                        wp_b, rpb1, rpb2,
                                                        lepe_w, lepe_b, lepe_s, lepe_bb,
                                                        mix_ws, out);
    final_k<<<dim3(25, BB), 256, 0, stream>>>(mix_ws, dy_w, dy_s, dy_bb, out);
}

// Round 19
// 228.634 us; speedup vs baseline: 1.0448x; 1.0062x over previous
//
#include <hip/hip_runtime.h>

#define BB 32
#define CC 64
#define HH 56
#define WW 56
#define HW 3136
#define TW 64
#define TR 12

// bf16 round-to-nearest-even pack/unpack (intermediates only)
__device__ __forceinline__ unsigned short f2bf(float f) {
    unsigned int u = __float_as_uint(f);
    u = (u + 0x7FFFu + ((u >> 16) & 1u)) >> 16;
    return (unsigned short)u;
}
__device__ __forceinline__ float bf2f(unsigned short h) {
    return __uint_as_float(((unsigned int)h) << 16);
}

// ---------------- prep: pool(8x8 mean) -> wk matmul+bn -> WK = wp * kg^T ----------------
__global__ __launch_bounds__(256) void prep_k(const float* __restrict__ x,
                                              const float* __restrict__ wk,
                                              const float* __restrict__ wks,
                                              const float* __restrict__ wkb,
                                              const float* __restrict__ wp_w,
                                              float* __restrict__ WK) {
    __shared__ float p_s[32 * 49];
    __shared__ float kg_s[8 * 49];
    const int b = blockIdx.x >> 2;
    const int g = blockIdx.x & 3;
    const int tid = threadIdx.x;
    for (int idx = tid; idx < 1568; idx += 256) {
        const int i = idx / 49, l = idx % 49;
        const int py = l / 7, px = l % 7;
        const float4* xp4 = reinterpret_cast<const float4*>(
            x + ((long)(b * CC + 32 + i)) * HW + py * 8 * WW + px * 8);
        float4 sA = make_float4(0.f, 0.f, 0.f, 0.f);
        float4 sB = make_float4(0.f, 0.f, 0.f, 0.f);
        #pragma unroll
        for (int y = 0; y < 8; ++y) {
            const float4 a = xp4[y * 14];
            const float4 c = xp4[y * 14 + 1];
            sA.x += a.x; sA.y += a.y; sA.z += a.z; sA.w += a.w;
            sB.x += c.x; sB.y += c.y; sB.z += c.z; sB.w += c.w;
        }
        p_s[idx] = (sA.x + sA.y + sA.z + sA.w + sB.x + sB.y + sB.z + sB.w) * (1.f / 64.f);
    }
    __syncthreads();
    for (int idx = tid; idx < 392; idx += 256) {
        const int o8 = idx / 49, l = idx % 49;
        const int o = g * 8 + o8;
        float acc = 0.f;
        #pragma unroll
        for (int i = 0; i < 32; ++i) acc = fmaf(wk[o * 32 + i], p_s[i * 49 + l], acc);
        kg_s[idx] = acc * wks[o] + wkb[o];
    }
    __syncthreads();
    for (int idx = tid; idx < 640; idx += 256) {
        const int c = idx / 80, slot = idx % 80;
        float acc = 0.f;
        int m = -1;
        if (slot < 28) { if (slot < 25) m = slot; }
        else           { if (slot < 77) m = 25 + (slot - 28); }
        if (m >= 0) {
            const float* kp = kg_s + c * 49;
            #pragma unroll
            for (int l = 0; l < 49; ++l) acc = fmaf(wp_w[m * 49 + l], kp[l], acc);
        }
        const long base = (long)blockIdx.x * 640;
        if (slot < 28) WK[base + c * 28 + slot] = acc;
        else           WK[base + 224 + c * 52 + (slot - 28)] = acc;
    }
}

// ---------------- fused q-proj + attention + dyn_mix + lepe ----------------
// r18 kernel verbatim except lepe is ALSO stored bf16 (to workspace, not out):
// final_k composes out = matmul*s+b + lepe, converting its fp32 RMW into a
// bf16 read + pure write.
__global__ __launch_bounds__(256) void attnmix_k(const float* __restrict__ x,
                                                 const float* __restrict__ WK,
                                                 const float* __restrict__ wq_w,
                                                 const float* __restrict__ wq_s,
                                                 const float* __restrict__ wq_bb,
                                                 const float* __restrict__ wp_b,
                                                 const float* __restrict__ rpb1,
                                                 const float* __restrict__ rpb2,
                                                 const float* __restrict__ lw,
                                                 const float* __restrict__ lb,
                                                 const float* __restrict__ ls,
                                                 const float* __restrict__ lbb,
                                                 unsigned short* __restrict__ mix,
                                                 unsigned short* __restrict__ lep) {
    __shared__ float tile[8 * TR * TW];   // 24 KB
    __shared__ float WK1_s[8 * 28];
    __shared__ float WK2_s[8 * 52];
    __shared__ float wqT_s[32 * 8];
    __shared__ float wpb1_s[25];
    __shared__ float wpb2_s[49];
    __shared__ float rpb1_s[81];
    __shared__ float rpb2_s[169];
    __shared__ float wqbn_s[16];
    __shared__ float lw_s[8 * 49];        // per-phase lepe weights (reloaded at phase 2)
    __shared__ float lbn_s[48];           // [0..15]=b, [16..31]=s, [32..47]=bb
    const int tid = threadIdx.x;
    const int bg = blockIdx.y;
    const int g = bg & 3, b = bg >> 2;

    {
        const float* wkp = WK + (long)bg * 640;
        for (int i = tid; i < 224; i += 256) WK1_s[i] = wkp[i];
        for (int i = tid; i < 416; i += 256) WK2_s[i] = wkp[224 + i];
    }
    {
        const int i = tid >> 3, c = tid & 7;
        wqT_s[tid] = wq_w[(g * 8 + c) * 32 + i];
    }
    if (tid < 25) wpb1_s[tid] = wp_b[tid];
    if (tid >= 32 && tid < 81) wpb2_s[tid - 32] = wp_b[25 + tid - 32];
    if (tid < 81) rpb1_s[tid] = rpb1[g * 81 + tid];
    if (tid < 169) rpb2_s[tid] = rpb2[g * 169 + tid];
    if (tid >= 192 && tid < 200) wqbn_s[tid - 192] = wq_s[g * 8 + tid - 192];
    if (tid >= 200 && tid < 208) wqbn_s[8 + tid - 200] = wq_bb[g * 8 + tid - 200];
    for (int i = tid; i < 392; i += 256) lw_s[i] = lw[(g * 8) * 49 + i];   // phase-1 chans
    if (tid < 16) {
        const int c = (tid < 8) ? (g * 8 + tid) : (32 + g * 8 + tid - 8);
        lbn_s[tid] = lb[c]; lbn_s[16 + tid] = ls[c]; lbn_s[32 + tid] = lbb[c];
    }

    const int N0 = blockIdx.x << 8;
    const int ph0 = N0 / WW;             // block-uniform
    const int r0 = ph0 - 3;

    // ---- stage v0 tile (channels g*8 .. g*8+8) ----
    {
        const float* xc = x + ((long)b * CC + g * 8) * HW;
        #pragma unroll
        for (int ch = 0; ch < 8; ++ch)
            for (int k = tid; k < TR * TW; k += 256) {
                const int row = k >> 6, lxx = k & 63;
                const int gy = r0 + row, gx = lxx - 3;
                float v = 0.f;
                if ((unsigned)gy < HH && (unsigned)gx < WW) v = xc[ch * HW + gy * WW + gx];
                tile[ch * (TR * TW) + k] = v;
            }
    }
    __syncthreads();

    const int n = N0 + tid;
    const bool valid = n < HW;
    const int nc = valid ? n : HW - 1;
    const int ph = nc / WW, pw = nc % WW;
    const int yr = HH - 1 - ph, xr = WW - 1 - pw;
    const int lrow = ph - r0;            // in [3, 8]
    const int tb0 = (lrow - 3) * TW + pw;   // tile offset of tap (i=0,j=0)

    const float* xb = x + (long)b * CC * HW + nc;

    // ---- q8: q = wq . x[0..32), bn, *SCALE ----
    float q8[8];
    #pragma unroll
    for (int c = 0; c < 8; ++c) q8[c] = 0.f;
    for (int i = 0; i < 32; ++i) {
        const float xv = xb[i * HW];
        #pragma unroll
        for (int c = 0; c < 8; ++c) q8[c] = fmaf(wqT_s[i * 8 + c], xv, q8[c]);
    }
    #pragma unroll
    for (int c = 0; c < 8; ++c)
        q8[c] = (q8[c] * wqbn_s[c] + wqbn_s[8 + c]) * 0.25f;

    __builtin_amdgcn_sched_barrier(0);

    // ======== phase 1: 25-weight softmax, 5x5 gather + lepe 7x7 over v0 ========
    {
        float w1[25];
        #pragma unroll
        for (int m = 0; m < 25; ++m) w1[m] = wpb1_s[m];
        #pragma unroll
        for (int c = 0; c < 8; ++c) {
            const float qv = q8[c];
            #pragma unroll
            for (int m = 0; m < 25; ++m) w1[m] = fmaf(qv, WK1_s[c * 28 + m], w1[m]);
        }
        const int rh5 = yr < 2 ? yr : (yr > 53 ? yr - 51 : 2);
        const int rw5 = xr < 2 ? xr : (xr > 53 ? xr - 51 : 2);
        #pragma unroll
        for (int i = 0; i < 5; ++i)
            #pragma unroll
            for (int j = 0; j < 5; ++j)
                w1[i * 5 + j] += rpb1_s[(rh5 + i) * 9 + (rw5 + j)];
        float mxa = -1e30f, mxb = -1e30f;
        #pragma unroll
        for (int m = 0; m < 24; m += 2) { mxa = fmaxf(mxa, w1[m]); mxb = fmaxf(mxb, w1[m + 1]); }
        const float mx = fmaxf(fmaxf(mxa, mxb), w1[24]);
        float sma = 0.f, smb = 0.f;
        #pragma unroll
        for (int m = 0; m < 24; m += 2) {
            w1[m] = __expf(w1[m] - mx);     sma += w1[m];
            w1[m + 1] = __expf(w1[m + 1] - mx); smb += w1[m + 1];
        }
        w1[24] = __expf(w1[24] - mx);
        const float r = 1.f / (sma + smb + w1[24]);
        #pragma unroll
        for (int m = 0; m < 25; ++m) w1[m] *= r;

        unsigned short* m0 = mix + ((long)b * CC + g * 8) * HW + nc;
        unsigned short* o0 = lep + ((long)b * CC + g * 8) * HW + nc;
        #pragma unroll
        for (int ch = 0; ch < 8; ++ch) {
            const float* t = tile + ch * (TR * TW) + tb0;
            const float* lwc = lw_s + ch * 49;
            float a_e = 0.f, a_o = 0.f, la_e = 0.f, la_o = 0.f;
            #pragma unroll
            for (int i = 0; i < 7; ++i)
                #pragma unroll
                for (int j = 0; j < 7; ++j) {
                    const float v = t[i * TW + j];
                    if (i & 1) {
                        la_o = fmaf(lwc[i * 7 + j], v, la_o);
                        if (i <= 5 && j >= 1 && j <= 5)
                            a_o = fmaf(w1[(i - 1) * 5 + (j - 1)], v, a_o);
                    } else {
                        la_e = fmaf(lwc[i * 7 + j], v, la_e);
                        if (i >= 1 && i <= 5 && j >= 1 && j <= 5)
                            a_e = fmaf(w1[(i - 1) * 5 + (j - 1)], v, a_e);
                    }
                }
            if (valid) {
                m0[ch * HW] = f2bf(a_e + a_o);
                o0[ch * HW] = f2bf(((la_e + la_o) + lbn_s[ch]) * lbn_s[16 + ch] + lbn_s[32 + ch]);
            }
        }
    }

    __syncthreads();                      // tile + lw reads done
    // ---- re-stage tile with v1 channels (32 + g*8 ..) + phase-2 lepe weights ----
    {
        const float* xc = x + ((long)b * CC + 32 + g * 8) * HW;
        #pragma unroll
        for (int ch = 0; ch < 8; ++ch)
            for (int k = tid; k < TR * TW; k += 256) {
                const int row = k >> 6, lxx = k & 63;
                const int gy = r0 + row, gx = lxx - 3;
                float v = 0.f;
                if ((unsigned)gy < HH && (unsigned)gx < WW) v = xc[ch * HW + gy * WW + gx];
                tile[ch * (TR * TW) + k] = v;
            }
        for (int i = tid; i < 392; i += 256) lw_s[i] = lw[(32 + g * 8) * 49 + i];
    }
    __syncthreads();

    // ======== phase 2: 49-weight softmax, 7x7 gather + lepe 7x7 over v1 ========
    {
        float w2[49];
        #pragma unroll
        for (int m = 0; m < 49; ++m) w2[m] = wpb2_s[m];
        #pragma unroll
        for (int c = 0; c < 8; ++c) {
            const float qv = q8[c];
            #pragma unroll
            for (int m = 0; m < 49; ++m) w2[m] = fmaf(qv, WK2_s[c * 52 + m], w2[m]);
        }
        const int rh7 = yr < 3 ? yr : (yr > 52 ? yr - 49 : 3);
        const int rw7 = xr < 3 ? xr : (xr > 52 ? xr - 49 : 3);
        #pragma unroll
        for (int i = 0; i < 7; ++i)
            #pragma unroll
            for (int j = 0; j < 7; ++j)
                w2[i * 7 + j] += rpb2_s[(rh7 + i) * 13 + (rw7 + j)];
        float mxa = -1e30f, mxb = -1e30f;
        #pragma unroll
        for (int m = 0; m < 48; m += 2) { mxa = fmaxf(mxa, w2[m]); mxb = fmaxf(mxb, w2[m + 1]); }
        const float mx = fmaxf(fmaxf(mxa, mxb), w2[48]);
        float sma = 0.f, smb = 0.f;
        #pragma unroll
        for (int m = 0; m < 48; m += 2) {
            w2[m] = __expf(w2[m] - mx);     sma += w2[m];
            w2[m + 1] = __expf(w2[m + 1] - mx); smb += w2[m + 1];
        }
        w2[48] = __expf(w2[48] - mx);
        const float r = 1.f / (sma + smb + w2[48]);
        #pragma unroll
        for (int m = 0; m < 49; ++m) w2[m] *= r;

        unsigned short* m1 = mix + ((long)b * CC + 32 + g * 8) * HW + nc;
        unsigned short* o1 = lep + ((long)b * CC + 32 + g * 8) * HW + nc;
        #pragma unroll
        for (int ch = 0; ch < 8; ++ch) {
            const float* t = tile + ch * (TR * TW) + tb0;
            const float* lwc = lw_s + ch * 49;
            float a_e = 0.f, a_o = 0.f, la_e = 0.f, la_o = 0.f;
            #pragma unroll
            for (int i = 0; i < 7; ++i)
                #pragma unroll
                for (int j = 0; j < 7; ++j) {
                    const float v = t[i * TW + j];
                    if (i & 1) {
                        la_o = fmaf(lwc[i * 7 + j], v, la_o);
                        a_o  = fmaf(w2[i * 7 + j], v, a_o);
                    } else {
                        la_e = fmaf(lwc[i * 7 + j], v, la_e);
                        a_e  = fmaf(w2[i * 7 + j], v, a_e);
                    }
                }
            if (valid) {
                m1[ch * HW] = f2bf(a_e + a_o);
                o1[ch * HW] = f2bf(((la_e + la_o) + lbn_s[8 + ch]) * lbn_s[16 + 8 + ch] + lbn_s[32 + 8 + ch]);
            }
        }
    }
}

// ---------------- final: 64x64 channel matmul + bn + lepe add (bf16 in, pure write) ----------------
__global__ __launch_bounds__(256) void final_k(const unsigned short* __restrict__ mix,
                                               const unsigned short* __restrict__ lep,
                                               const float* __restrict__ dy_w,
                                               const float* __restrict__ s,
                                               const float* __restrict__ bb,
                                               float* __restrict__ out) {
    __shared__ float w_s[64 * 64];      // transposed: w_s[i*64+o] = dy_w[o*64+i]
    const int tid = threadIdx.x;
    const int b = blockIdx.y;
    for (int i = tid; i < 4096; i += 256) w_s[(i & 63) * 64 + (i >> 6)] = dy_w[i];
    __syncthreads();
    const int oo = (tid >> 5) * 8;
    const int p4 = blockIdx.x * 32 + (tid & 31);
    if (p4 >= 784) return;
    const unsigned short* mp = mix + (long)b * CC * HW + p4 * 4;
    const unsigned short* lp = lep + (long)b * CC * HW + p4 * 4;
    float4 acc[8];
    #pragma unroll
    for (int o = 0; o < 8; ++o) acc[o] = make_float4(0.f, 0.f, 0.f, 0.f);
    for (int ii = 0; ii < 64; ii += 8) {
        float4 mv[8];
        #pragma unroll
        for (int u = 0; u < 8; ++u) {
            const ushort4 h = *reinterpret_cast<const ushort4*>(mp + (long)(ii + u) * HW);
            mv[u].x = bf2f(h.x); mv[u].y = bf2f(h.y);
            mv[u].z = bf2f(h.z); mv[u].w = bf2f(h.w);
        }
        #pragma unroll
        for (int u = 0; u < 8; ++u) {
            const float* wr = w_s + (ii + u) * 64 + oo;
            #pragma unroll
            for (int o = 0; o < 8; ++o) {
                const float wv = wr[o];
                acc[o].x = fmaf(wv, mv[u].x, acc[o].x);
                acc[o].y = fmaf(wv, mv[u].y, acc[o].y);
                acc[o].z = fmaf(wv, mv[u].z, acc[o].z);
                acc[o].w = fmaf(wv, mv[u].w, acc[o].w);
            }
        }
    }
    float* op = out + (long)b * CC * HW + p4 * 4;
    #pragma unroll
    for (int o = 0; o < 8; ++o) {
        const float sc = s[oo + o], bc = bb[oo + o];
        const ushort4 lh = *reinterpret_cast<const ushort4*>(lp + (long)(oo + o) * HW);
        float4 r;
        r.x = fmaf(acc[o].x, sc, bc) + bf2f(lh.x);
        r.y = fmaf(acc[o].y, sc, bc) + bf2f(lh.y);
        r.z = fmaf(acc[o].z, sc, bc) + bf2f(lh.z);
        r.w = fmaf(acc[o].w, sc, bc) + bf2f(lh.w);
        *reinterpret_cast<float4*>(op + (long)(oo + o) * HW) = r;
    }
}

extern "C" void kernel_launch(void* const* d_in, const int* in_sizes, int n_in,
                              void* d_out, int out_size, void* d_ws, size_t ws_size,
                              hipStream_t stream) {
    const float* x       = (const float*)d_in[0];
    const float* lepe_w  = (const float*)d_in[1];
    const float* lepe_b  = (const float*)d_in[2];
    const float* lepe_s  = (const float*)d_in[3];
    const float* lepe_bb = (const float*)d_in[4];
    const float* wq_w    = (const float*)d_in[5];
    const float* wq_s    = (const float*)d_in[6];
    const float* wq_bb   = (const float*)d_in[7];
    const float* wk_w    = (const float*)d_in[8];
    const float* wk_s    = (const float*)d_in[9];
    const float* wk_bb   = (const float*)d_in[10];
    const float* wp_w    = (const float*)d_in[11];
    const float* wp_b    = (const float*)d_in[12];
    const float* rpb1    = (const float*)d_in[13];
    const float* rpb2    = (const float*)d_in[14];
    const float* dy_w    = (const float*)d_in[15];
    const float* dy_s    = (const float*)d_in[16];
    const float* dy_bb   = (const float*)d_in[17];
    float* out = (float*)d_out;

    float* ws     = (float*)d_ws;
    float* WK_ws  = ws;                                            // 128*640 floats
    unsigned short* mix_ws = (unsigned short*)(WK_ws + 128 * 640); // 32*64*3136 bf16
    unsigned short* lep_ws = mix_ws + (long)32 * 64 * HW;          // 32*64*3136 bf16

    const int nTiles = (HW + 255) / 256;              // 13

    prep_k<<<dim3(BB * 4), 256, 0, stream>>>(x, wk_w, wk_s, wk_bb, wp_w, WK_ws);
    attnmix_k<<<dim3(nTiles, BB * 4), 256, 0, stream>>>(x, WK_ws, wq_w, wq_s, wq_bb,
                                                        wp_b, rpb1, rpb2,
                                                        lepe_w, lepe_b, lepe_s, lepe_bb,
                                                        mix_ws, lep_ws);
    final_k<<<dim3(25, BB), 256, 0, stream>>>(mix_ws, lep_ws, dy_w, dy_s, dy_bb, out);
}

// Round 21
// 227.616 us; speedup vs baseline: 1.0495x; 1.0045x over previous
//
#include <hip/hip_runtime.h>

#define BB 32
#define CC 64
#define HH 56
#define WW 56
#define HW 3136
#define TW 64
#define TR 12

// bf16 RNE pack (intermediates only)
__device__ __forceinline__ unsigned int f2bf_bits(float f) {
    unsigned int u = __float_as_uint(f);
    return (u + 0x7FFFu + ((u >> 16) & 1u)) >> 16;   // bf16 bits in lo16
}

// ---------------- prep: pool(8x8 mean) -> wk matmul+bn -> WK = wp * kg^T ----------------
__global__ __launch_bounds__(256) void prep_k(const float* __restrict__ x,
                                              const float* __restrict__ wk,
                                              const float* __restrict__ wks,
                                              const float* __restrict__ wkb,
                                              const float* __restrict__ wp_w,
                                              float* __restrict__ WK) {
    __shared__ float p_s[32 * 49];
    __shared__ float kg_s[8 * 49];
    const int b = blockIdx.x >> 2;
    const int g = blockIdx.x & 3;
    const int tid = threadIdx.x;
    for (int idx = tid; idx < 1568; idx += 256) {
        const int i = idx / 49, l = idx % 49;
        const int py = l / 7, px = l % 7;
        const float4* xp4 = reinterpret_cast<const float4*>(
            x + ((long)(b * CC + 32 + i)) * HW + py * 8 * WW + px * 8);
        float4 sA = make_float4(0.f, 0.f, 0.f, 0.f);
        float4 sB = make_float4(0.f, 0.f, 0.f, 0.f);
        #pragma unroll
        for (int y = 0; y < 8; ++y) {
            const float4 a = xp4[y * 14];
            const float4 c = xp4[y * 14 + 1];
            sA.x += a.x; sA.y += a.y; sA.z += a.z; sA.w += a.w;
            sB.x += c.x; sB.y += c.y; sB.z += c.z; sB.w += c.w;
        }
        p_s[idx] = (sA.x + sA.y + sA.z + sA.w + sB.x + sB.y + sB.z + sB.w) * (1.f / 64.f);
    }
    __syncthreads();
    for (int idx = tid; idx < 392; idx += 256) {
        const int o8 = idx / 49, l = idx % 49;
        const int o = g * 8 + o8;
        float acc = 0.f;
        #pragma unroll
        for (int i = 0; i < 32; ++i) acc = fmaf(wk[o * 32 + i], p_s[i * 49 + l], acc);
        kg_s[idx] = acc * wks[o] + wkb[o];
    }
    __syncthreads();
    for (int idx = tid; idx < 640; idx += 256) {
        const int c = idx / 80, slot = idx % 80;
        float acc = 0.f;
        int m = -1;
        if (slot < 28) { if (slot < 25) m = slot; }
        else           { if (slot < 77) m = 25 + (slot - 28); }
        if (m >= 0) {
            const float* kp = kg_s + c * 49;
            #pragma unroll
            for (int l = 0; l < 49; ++l) acc = fmaf(wp_w[m * 49 + l], kp[l], acc);
        }
        const long base = (long)blockIdx.x * 640;
        if (slot < 28) WK[base + c * 28 + slot] = acc;
        else           WK[base + 224 + c * 52 + (slot - 28)] = acc;
    }
}

// ---------------- fused q-proj + attention + dyn_mix + lepe ----------------
// r19 numerics verbatim; mix(bf16, lo16) and lepe(bf16, hi16) PACKED into one uint
// per (channel,pixel): 16 dword stores/thread (r19's 32 sub-dword stores were the
// suspected regression). Traffic unchanged vs r19.
__global__ __launch_bounds__(256) void attnmix_k(const float* __restrict__ x,
                                                 const float* __restrict__ WK,
                                                 const float* __restrict__ wq_w,
                                                 const float* __restrict__ wq_s,
                                                 const float* __restrict__ wq_bb,
                                                 const float* __restrict__ wp_b,
                                                 const float* __restrict__ rpb1,
                                                 const float* __restrict__ rpb2,
                                                 const float* __restrict__ lw,
                                                 const float* __restrict__ lb,
                                                 const float* __restrict__ ls,
                                                 const float* __restrict__ lbb,
                                                 unsigned int* __restrict__ cmb) {
    __shared__ float tile[8 * TR * TW];   // 24 KB
    __shared__ float WK1_s[8 * 28];
    __shared__ float WK2_s[8 * 52];
    __shared__ float wqT_s[32 * 8];
    __shared__ float wpb1_s[25];
    __shared__ float wpb2_s[49];
    __shared__ float rpb1_s[81];
    __shared__ float rpb2_s[169];
    __shared__ float wqbn_s[16];
    __shared__ float lw_s[8 * 49];        // per-phase lepe weights (reloaded at phase 2)
    __shared__ float lbn_s[48];           // [0..15]=b, [16..31]=s, [32..47]=bb
    const int tid = threadIdx.x;
    const int bg = blockIdx.y;
    const int g = bg & 3, b = bg >> 2;

    {
        const float* wkp = WK + (long)bg * 640;
        for (int i = tid; i < 224; i += 256) WK1_s[i] = wkp[i];
        for (int i = tid; i < 416; i += 256) WK2_s[i] = wkp[224 + i];
    }
    {
        const int i = tid >> 3, c = tid & 7;
        wqT_s[tid] = wq_w[(g * 8 + c) * 32 + i];
    }
    if (tid < 25) wpb1_s[tid] = wp_b[tid];
    if (tid >= 32 && tid < 81) wpb2_s[tid - 32] = wp_b[25 + tid - 32];
    if (tid < 81) rpb1_s[tid] = rpb1[g * 81 + tid];
    if (tid < 169) rpb2_s[tid] = rpb2[g * 169 + tid];
    if (tid >= 192 && tid < 200) wqbn_s[tid - 192] = wq_s[g * 8 + tid - 192];
    if (tid >= 200 && tid < 208) wqbn_s[8 + tid - 200] = wq_bb[g * 8 + tid - 200];
    for (int i = tid; i < 392; i += 256) lw_s[i] = lw[(g * 8) * 49 + i];   // phase-1 chans
    if (tid < 16) {
        const int c = (tid < 8) ? (g * 8 + tid) : (32 + g * 8 + tid - 8);
        lbn_s[tid] = lb[c]; lbn_s[16 + tid] = ls[c]; lbn_s[32 + tid] = lbb[c];
    }

    const int N0 = blockIdx.x << 8;
    const int ph0 = N0 / WW;             // block-uniform
    const int r0 = ph0 - 3;

    // ---- stage v0 tile (channels g*8 .. g*8+8) ----
    {
        const float* xc = x + ((long)b * CC + g * 8) * HW;
        #pragma unroll
        for (int ch = 0; ch < 8; ++ch)
            for (int k = tid; k < TR * TW; k += 256) {
                const int row = k >> 6, lxx = k & 63;
                const int gy = r0 + row, gx = lxx - 3;
                float v = 0.f;
                if ((unsigned)gy < HH && (unsigned)gx < WW) v = xc[ch * HW + gy * WW + gx];
                tile[ch * (TR * TW) + k] = v;
            }
    }
    __syncthreads();

    const int n = N0 + tid;
    const bool valid = n < HW;
    const int nc = valid ? n : HW - 1;
    const int ph = nc / WW, pw = nc % WW;
    const int yr = HH - 1 - ph, xr = WW - 1 - pw;
    const int lrow = ph - r0;            // in [3, 8]
    const int tb0 = (lrow - 3) * TW + pw;   // tile offset of tap (i=0,j=0)

    const float* xb = x + (long)b * CC * HW + nc;

    // ---- q8: q = wq . x[0..32), bn, *SCALE ----
    float q8[8];
    #pragma unroll
    for (int c = 0; c < 8; ++c) q8[c] = 0.f;
    for (int i = 0; i < 32; ++i) {
        const float xv = xb[i * HW];
        #pragma unroll
        for (int c = 0; c < 8; ++c) q8[c] = fmaf(wqT_s[i * 8 + c], xv, q8[c]);
    }
    #pragma unroll
    for (int c = 0; c < 8; ++c)
        q8[c] = (q8[c] * wqbn_s[c] + wqbn_s[8 + c]) * 0.25f;

    __builtin_amdgcn_sched_barrier(0);

    // ======== phase 1: 25-weight softmax, 5x5 gather + lepe 7x7 over v0 ========
    {
        float w1[25];
        #pragma unroll
        for (int m = 0; m < 25; ++m) w1[m] = wpb1_s[m];
        #pragma unroll
        for (int c = 0; c < 8; ++c) {
            const float qv = q8[c];
            #pragma unroll
            for (int m = 0; m < 25; ++m) w1[m] = fmaf(qv, WK1_s[c * 28 + m], w1[m]);
        }
        const int rh5 = yr < 2 ? yr : (yr > 53 ? yr - 51 : 2);
        const int rw5 = xr < 2 ? xr : (xr > 53 ? xr - 51 : 2);
        #pragma unroll
        for (int i = 0; i < 5; ++i)
            #pragma unroll
            for (int j = 0; j < 5; ++j)
                w1[i * 5 + j] += rpb1_s[(rh5 + i) * 9 + (rw5 + j)];
        float mxa = -1e30f, mxb = -1e30f;
        #pragma unroll
        for (int m = 0; m < 24; m += 2) { mxa = fmaxf(mxa, w1[m]); mxb = fmaxf(mxb, w1[m + 1]); }
        const float mx = fmaxf(fmaxf(mxa, mxb), w1[24]);
        float sma = 0.f, smb = 0.f;
        #pragma unroll
        for (int m = 0; m < 24; m += 2) {
            w1[m] = __expf(w1[m] - mx);     sma += w1[m];
            w1[m + 1] = __expf(w1[m + 1] - mx); smb += w1[m + 1];
        }
        w1[24] = __expf(w1[24] - mx);
        const float r = 1.f / (sma + smb + w1[24]);
        #pragma unroll
        for (int m = 0; m < 25; ++m) w1[m] *= r;

        unsigned int* c0 = cmb + ((long)b * CC + g * 8) * HW + nc;
        #pragma unroll
        for (int ch = 0; ch < 8; ++ch) {
            const float* t = tile + ch * (TR * TW) + tb0;
            const float* lwc = lw_s + ch * 49;
            float a_e = 0.f, a_o = 0.f, la_e = 0.f, la_o = 0.f;
            #pragma unroll
            for (int i = 0; i < 7; ++i)
                #pragma unroll
                for (int j = 0; j < 7; ++j) {
                    const float v = t[i * TW + j];
                    if (i & 1) {
                        la_o = fmaf(lwc[i * 7 + j], v, la_o);
                        if (i <= 5 && j >= 1 && j <= 5)
                            a_o = fmaf(w1[(i - 1) * 5 + (j - 1)], v, a_o);
                    } else {
                        la_e = fmaf(lwc[i * 7 + j], v, la_e);
                        if (i >= 1 && i <= 5 && j >= 1 && j <= 5)
                            a_e = fmaf(w1[(i - 1) * 5 + (j - 1)], v, a_e);
                    }
                }
            if (valid) {
                const float lv = ((la_e + la_o) + lbn_s[ch]) * lbn_s[16 + ch] + lbn_s[32 + ch];
                c0[ch * HW] = f2bf_bits(a_e + a_o) | (f2bf_bits(lv) << 16);
            }
        }
    }

    __syncthreads();                      // tile + lw reads done
    // ---- re-stage tile with v1 channels (32 + g*8 ..) + phase-2 lepe weights ----
    {
        const float* xc = x + ((long)b * CC + 32 + g * 8) * HW;
        #pragma unroll
        for (int ch = 0; ch < 8; ++ch)
            for (int k = tid; k < TR * TW; k += 256) {
                const int row = k >> 6, lxx = k & 63;
                const int gy = r0 + row, gx = lxx - 3;
                float v = 0.f;
                if ((unsigned)gy < HH && (unsigned)gx < WW) v = xc[ch * HW + gy * WW + gx];
                tile[ch * (TR * TW) + k] = v;
            }
        for (int i = tid; i < 392; i += 256) lw_s[i] = lw[(32 + g * 8) * 49 + i];
    }
    __syncthreads();

    // ======== phase 2: 49-weight softmax, 7x7 gather + lepe 7x7 over v1 ========
    {
        float w2[49];
        #pragma unroll
        for (int m = 0; m < 49; ++m) w2[m] = wpb2_s[m];
        #pragma unroll
        for (int c = 0; c < 8; ++c) {
            const float qv = q8[c];
            #pragma unroll
            for (int m = 0; m < 49; ++m) w2[m] = fmaf(qv, WK2_s[c * 52 + m], w2[m]);
        }
        const int rh7 = yr < 3 ? yr : (yr > 52 ? yr - 49 : 3);
        const int rw7 = xr < 3 ? xr : (xr > 52 ? xr - 49 : 3);
        #pragma unroll
        for (int i = 0; i < 7; ++i)
            #pragma unroll
            for (int j = 0; j < 7; ++j)
                w2[i * 7 + j] += rpb2_s[(rh7 + i) * 13 + (rw7 + j)];
        float mxa = -1e30f, mxb = -1e30f;
        #pragma unroll
        for (int m = 0; m < 48; m += 2) { mxa = fmaxf(mxa, w2[m]); mxb = fmaxf(mxb, w2[m + 1]); }
        const float mx = fmaxf(fmaxf(mxa, mxb), w2[48]);
        float sma = 0.f, smb = 0.f;
        #pragma unroll
        for (int m = 0; m < 48; m += 2) {
            w2[m] = __expf(w2[m] - mx);     sma += w2[m];
            w2[m + 1] = __expf(w2[m + 1] - mx); smb += w2[m + 1];
        }
        w2[48] = __expf(w2[48] - mx);
        const float r = 1.f / (sma + smb + w2[48]);
        #pragma unroll
        for (int m = 0; m < 49; ++m) w2[m] *= r;

        unsigned int* c1 = cmb + ((long)b * CC + 32 + g * 8) * HW + nc;
        #pragma unroll
        for (int ch = 0; ch < 8; ++ch) {
            const float* t = tile + ch * (TR * TW) + tb0;
            const float* lwc = lw_s + ch * 49;
            float a_e = 0.f, a_o = 0.f, la_e = 0.f, la_o = 0.f;
            #pragma unroll
            for (int i = 0; i < 7; ++i)
                #pragma unroll
                for (int j = 0; j < 7; ++j) {
                    const float v = t[i * TW + j];
                    if (i & 1) {
                        la_o = fmaf(lwc[i * 7 + j], v, la_o);
                        a_o  = fmaf(w2[i * 7 + j], v, a_o);
                    } else {
                        la_e = fmaf(lwc[i * 7 + j], v, la_e);
                        a_e  = fmaf(w2[i * 7 + j], v, a_e);
                    }
                }
            if (valid) {
                const float lv = ((la_e + la_o) + lbn_s[8 + ch]) * lbn_s[16 + 8 + ch] + lbn_s[32 + 8 + ch];
                c1[ch * HW] = f2bf_bits(a_e + a_o) | (f2bf_bits(lv) << 16);
            }
        }
    }
}

// ---------------- final: 64x64 channel matmul + bn + lepe add (packed bf16 in) ----------------
__global__ __launch_bounds__(256) void final_k(const unsigned int* __restrict__ cmb,
                                               const float* __restrict__ dy_w,
                                               const float* __restrict__ s,
                                               const float* __restrict__ bb,
                                               float* __restrict__ out) {
    __shared__ float w_s[64 * 64];      // transposed: w_s[i*64+o] = dy_w[o*64+i]
    const int tid = threadIdx.x;
    const int b = blockIdx.y;
    for (int i = tid; i < 4096; i += 256) w_s[(i & 63) * 64 + (i >> 6)] = dy_w[i];
    __syncthreads();
    const int oo = (tid >> 5) * 8;
    const int p4 = blockIdx.x * 32 + (tid & 31);
    if (p4 >= 784) return;
    const unsigned int* mp = cmb + (long)b * CC * HW + p4 * 4;
    float4 acc[8];
    #pragma unroll
    for (int o = 0; o < 8; ++o) acc[o] = make_float4(0.f, 0.f, 0.f, 0.f);
    for (int ii = 0; ii < 64; ii += 8) {
        float4 mv[8];
        #pragma unroll
        for (int u = 0; u < 8; ++u) {
            const uint4 h = *reinterpret_cast<const uint4*>(mp + (long)(ii + u) * HW);
            mv[u].x = __uint_as_float(h.x << 16); mv[u].y = __uint_as_float(h.y << 16);
            mv[u].z = __uint_as_float(h.z << 16); mv[u].w = __uint_as_float(h.w << 16);
        }
        #pragma unroll
        for (int u = 0; u < 8; ++u) {
            const float* wr = w_s + (ii + u) * 64 + oo;
            #pragma unroll
            for (int o = 0; o < 8; ++o) {
                const float wv = wr[o];
                acc[o].x = fmaf(wv, mv[u].x, acc[o].x);
                acc[o].y = fmaf(wv, mv[u].y, acc[o].y);
                acc[o].z = fmaf(wv, mv[u].z, acc[o].z);
                acc[o].w = fmaf(wv, mv[u].w, acc[o].w);
            }
        }
    }
    float* op = out + (long)b * CC * HW + p4 * 4;
    #pragma unroll
    for (int o = 0; o < 8; ++o) {
        const float sc = s[oo + o], bc = bb[oo + o];
        const uint4 lh = *reinterpret_cast<const uint4*>(mp + (long)(oo + o) * HW);  // L2-hot
        float4 r;
        r.x = fmaf(acc[o].x, sc, bc) + __uint_as_float(lh.x & 0xFFFF0000u);
        r.y = fmaf(acc[o].y, sc, bc) + __uint_as_float(lh.y & 0xFFFF0000u);
        r.z = fmaf(acc[o].z, sc, bc) + __uint_as_float(lh.z & 0xFFFF0000u);
        r.w = fmaf(acc[o].w, sc, bc) + __uint_as_float(lh.w & 0xFFFF0000u);
        *reinterpret_cast<float4*>(op + (long)(oo + o) * HW) = r;
    }
}

extern "C" void kernel_launch(void* const* d_in, const int* in_sizes, int n_in,
                              void* d_out, int out_size, void* d_ws, size_t ws_size,
                              hipStream_t stream) {
    const float* x       = (const float*)d_in[0];
    const float* lepe_w  = (const float*)d_in[1];
    const float* lepe_b  = (const float*)d_in[2];
    const float* lepe_s  = (const float*)d_in[3];
    const float* lepe_bb = (const float*)d_in[4];
    const float* wq_w    = (const float*)d_in[5];
    const float* wq_s    = (const float*)d_in[6];
    const float* wq_bb   = (const float*)d_in[7];
    const float* wk_w    = (const float*)d_in[8];
    const float* wk_s    = (const float*)d_in[9];
    const float* wk_bb   = (const float*)d_in[10];
    const float* wp_w    = (const float*)d_in[11];
    const float* wp_b    = (const float*)d_in[12];
    const float* rpb1    = (const float*)d_in[13];
    const float* rpb2    = (const float*)d_in[14];
    const float* dy_w    = (const float*)d_in[15];
    const float* dy_s    = (const float*)d_in[16];
    const float* dy_bb   = (const float*)d_in[17];
    float* out = (float*)d_out;

    float* ws     = (float*)d_ws;
    float* WK_ws  = ws;                                          // 128*640 floats
    unsigned int* cmb_ws = (unsigned int*)(WK_ws + 128 * 640);   // 32*64*3136 packed

    const int nTiles = (HW + 255) / 256;              // 13

    prep_k<<<dim3(BB * 4), 256, 0, stream>>>(x, wk_w, wk_s, wk_bb, wp_w, WK_ws);
    attnmix_k<<<dim3(nTiles, BB * 4), 256, 0, stream>>>(x, WK_ws, wq_w, wq_s, wq_bb,
                                                        wp_b, rpb1, rpb2,
                                                        lepe_w, lepe_b, lepe_s, lepe_bb,
                                                        cmb_ws);
    final_k<<<dim3(25, BB), 256, 0, stream>>>(cmb_ws, dy_w, dy_s, dy_bb, out);
}